// Round 4
// baseline (416.717 us; speedup 1.0000x reference)
//
#include <hip/hip_runtime.h>

// Fused 7-layer 1x1-conv chain, single-wave workgroups, ZERO barriers.
// Each block = 1 wave = 64 contiguous pixels. The wave stages its entire
// 128ch x 64px x-slice (32 KB) into wave-private LDS with 32 back-to-back
// global_load_lds (16B/lane) instructions -> one s_waitcnt -> L1-L3 bf16 MFMA
// (fragment math verified in rounds 2-3, absmax 1.5) -> L4-L7 fp32 VALU tail.
// Concurrency comes from 32 KB of async loads in flight per wave x 4 blocks/CU
// (LDS = 40,000 B/block), not from wave count; no __syncthreads anywhere.
//
// MFMA 16x16x32 layouts: A[m][k]: m=lane&15, k=(lane>>4)*8+j
//                        B[k][n]: n=lane&15, k=(lane>>4)*8+j
//                        C/D: col=lane&15, row=(lane>>4)*4+reg

#define NEG_SLOPE 0.01f
constexpr int HW = 65536;  // 256*256

typedef __attribute__((ext_vector_type(8))) short bf16x8;
typedef __attribute__((ext_vector_type(4))) float f32x4;

__device__ __forceinline__ float leaky(float v) { return v >= 0.f ? v : NEG_SLOPE * v; }

__device__ __forceinline__ short f2b(float f) {  // RNE fp32->bf16
    unsigned u = __float_as_uint(f);
    u += 0x7fffu + ((u >> 16) & 1u);
    return (short)(u >> 16);
}
__device__ __forceinline__ unsigned pk2(float a, float b) {
    return (unsigned)(unsigned short)f2b(a) | ((unsigned)(unsigned short)f2b(b) << 16);
}

// A-frag from o-major fp32 weight matrix W[m][k] (row length C); k 8-aligned
__device__ __forceinline__ bf16x8 loadA(const float* __restrict__ wsrc, int C, int m, int k) {
    f32x4 lo = *(const f32x4*)(wsrc + m * C + k);
    f32x4 hi = *(const f32x4*)(wsrc + m * C + k + 4);
    union { bf16x8 v; unsigned u[4]; } r;
    r.u[0] = pk2(lo[0], lo[1]); r.u[1] = pk2(lo[2], lo[3]);
    r.u[2] = pk2(hi[0], hi[1]); r.u[3] = pk2(hi[2], hi[3]);
    return r.v;
}

__device__ __forceinline__ void async_cp16(const float* g, float* l) {
    __builtin_amdgcn_global_load_lds((const __attribute__((address_space(1))) unsigned*)g,
                                     (__attribute__((address_space(3))) unsigned*)l,
                                     16, 0, 0);
}

__global__ __launch_bounds__(64) void fused_wave_kernel(
    const float* __restrict__ x,
    const float* __restrict__ w1, const float* __restrict__ w2,
    const float* __restrict__ w3, const float* __restrict__ w4,
    const float* __restrict__ w5, const float* __restrict__ w6,
    const float* __restrict__ w7, float* __restrict__ out) {
    __shared__ float lds_x[128 * 64];              // [ch][px], 32768 B, async-staged
    __shared__ alignas(16) short lds_h[16 * 68];   // h1 (16px x 68sh); h2 overlays (16px x 36sh)
    __shared__ float lds_h3[64 * 17];              // [px][ch], stride 17 (2-way reads = free)
    __shared__ float lds_tw[176];                  // tail weights w4|w5|w6|w7

    const int lane = threadIdx.x;  // block = 1 wave
    const int n    = lane & 15;    // frag minor index (pixel for B/D, row for A)
    const int q    = lane >> 4;    // quad

    const int px0   = blockIdx.x * 64;  // wave's 64 contiguous pixels (batch-uniform)
    const int batch = px0 >> 16;
    const int pin   = px0 & (HW - 1);
    const float* xg = x + (size_t)batch * 128 * HW + pin;

    // ---- stage ALL 128 channels (32 KB) with 32 back-to-back async instructions ----
    // instr i covers channels 4i..4i+3: lane reads ch = 4i + (lane>>4), px = (lane&15)*4..+3;
    // LDS dst is uniform-base + lane*16 (HW requirement) => rows land contiguously.
#pragma unroll
    for (int i = 0; i < 32; ++i)
        async_cp16(xg + (size_t)(i * 4 + q) * HW + n * 4, &lds_x[i * 256]);

    // ---- tail weights -> LDS (170 floats; VGPR loads, in-flight with staging) ----
#pragma unroll
    for (int t0 = 0; t0 < 3; ++t0) {
        int t = t0 * 64 + lane;
        float v = 0.f;
        if (t < 128)      v = w4[t];
        else if (t < 160) v = w5[t - 128];
        else if (t < 168) v = w6[t - 160];
        else if (t < 170) v = w7[t - 168];
        if (t < 170) lds_tw[t] = v;
    }

    // ---- weight A-frags into VGPRs (L2-hot after first blocks) ----
    bf16x8 a1[4][4];  // L1: M=64 (4 Mt) x K=128 (4 kc)
#pragma unroll
    for (int Mt = 0; Mt < 4; ++Mt)
#pragma unroll
        for (int kc = 0; kc < 4; ++kc)
            a1[Mt][kc] = loadA(w1, 128, Mt * 16 + n, kc * 32 + q * 8);
    bf16x8 a2[2][2];  // L2: M=32 x K=64
#pragma unroll
    for (int Mt = 0; Mt < 2; ++Mt)
#pragma unroll
        for (int kc = 0; kc < 2; ++kc)
            a2[Mt][kc] = loadA(w2, 64, Mt * 16 + n, kc * 32 + q * 8);
    bf16x8 a3 = loadA(w3, 32, n, q * 8);  // L3: M=16 x K=32

    // single drain: all async LDS stores + weight loads complete
    __builtin_amdgcn_s_waitcnt(0);

    // ---- per 16-px tile: L1 -> L2 -> L3 (all intra-wave, in-order DS => no barriers) ----
#pragma unroll
    for (int Nt = 0; Nt < 4; ++Nt) {
        // L1: K=128 in 4 chunks
        f32x4 acc1[4];
#pragma unroll
        for (int Mt = 0; Mt < 4; ++Mt) acc1[Mt] = (f32x4){0.f, 0.f, 0.f, 0.f};
#pragma unroll
        for (int kc = 0; kc < 4; ++kc) {
            float t[8];
#pragma unroll
            for (int j = 0; j < 8; ++j)
                t[j] = lds_x[(kc * 32 + q * 8 + j) * 64 + Nt * 16 + n];
            union { bf16x8 v; unsigned u[4]; } b;
            b.u[0] = pk2(t[0], t[1]); b.u[1] = pk2(t[2], t[3]);
            b.u[2] = pk2(t[4], t[5]); b.u[3] = pk2(t[6], t[7]);
#pragma unroll
            for (int Mt = 0; Mt < 4; ++Mt)
                acc1[Mt] = __builtin_amdgcn_mfma_f32_16x16x32_bf16(a1[Mt][kc], b.v, acc1[Mt], 0, 0, 0);
        }

        // h1: px=n (tile-local), ch = Mt*16 + q*4 + reg; stride 68 shorts
#pragma unroll
        for (int Mt = 0; Mt < 4; ++Mt) {
            uint2 v;
            v.x = pk2(leaky(acc1[Mt][0]), leaky(acc1[Mt][1]));
            v.y = pk2(leaky(acc1[Mt][2]), leaky(acc1[Mt][3]));
            *(uint2*)(lds_h + n * 68 + Mt * 16 + q * 4) = v;  // byte off 136n+32Mt+8q, 8-aligned
        }

        // L2: K=64 in 2 chunks, B-frags from h1
        f32x4 acc2[2];
#pragma unroll
        for (int Mt = 0; Mt < 2; ++Mt) acc2[Mt] = (f32x4){0.f, 0.f, 0.f, 0.f};
#pragma unroll
        for (int kc = 0; kc < 2; ++kc) {
            const short* src = lds_h + n * 68 + kc * 32 + q * 8;
            uint2 lo = *(const uint2*)src;
            uint2 hi = *(const uint2*)(src + 4);
            union { bf16x8 v; unsigned u[4]; } b;
            b.u[0] = lo.x; b.u[1] = lo.y; b.u[2] = hi.x; b.u[3] = hi.y;
#pragma unroll
            for (int Mt = 0; Mt < 2; ++Mt)
                acc2[Mt] = __builtin_amdgcn_mfma_f32_16x16x32_bf16(a2[Mt][kc], b.v, acc2[Mt], 0, 0, 0);
        }

        // h2 overlays h1 (all h1 reads precede in program order; per-wave DS is in-order)
#pragma unroll
        for (int Mt = 0; Mt < 2; ++Mt) {
            uint2 v;
            v.x = pk2(leaky(acc2[Mt][0]), leaky(acc2[Mt][1]));
            v.y = pk2(leaky(acc2[Mt][2]), leaky(acc2[Mt][3]));
            *(uint2*)(lds_h + n * 36 + Mt * 16 + q * 4) = v;
        }

        // L3: single MFMA, B-frag from h2
        {
            const short* src = lds_h + n * 36 + q * 8;
            uint2 lo = *(const uint2*)src;
            uint2 hi = *(const uint2*)(src + 4);
            union { bf16x8 v; unsigned u[4]; } b;
            b.u[0] = lo.x; b.u[1] = lo.y; b.u[2] = hi.x; b.u[3] = hi.y;
            f32x4 zero = {0.f, 0.f, 0.f, 0.f};
            f32x4 d3 = __builtin_amdgcn_mfma_f32_16x16x32_bf16(a3, b.v, zero, 0, 0, 0);
            // h3: global-tile px row, ch = q*4 + r; stride 17 floats, scalar stores
            float* h3w = lds_h3 + (Nt * 16 + n) * 17 + q * 4;
            h3w[0] = leaky(d3[0]);
            h3w[1] = leaky(d3[1]);
            h3w[2] = leaky(d3[2]);
            h3w[3] = leaky(d3[3]);
        }
    }

    // ---- tail L4-L7: one pixel per lane, weights broadcast from LDS ----
    float hh[16];
#pragma unroll
    for (int c = 0; c < 16; ++c) hh[c] = lds_h3[lane * 17 + c];  // 2-way = free

    float g4[8];
#pragma unroll
    for (int o = 0; o < 8; ++o) {
        float a = 0.f;
#pragma unroll
        for (int c = 0; c < 16; ++c) a = fmaf(lds_tw[o * 16 + c], hh[c], a);
        g4[o] = leaky(a);
    }
    float g5[4];
#pragma unroll
    for (int o = 0; o < 4; ++o) {
        float a = 0.f;
#pragma unroll
        for (int c = 0; c < 8; ++c) a = fmaf(lds_tw[128 + o * 8 + c], g4[c], a);
        g5[o] = leaky(a);
    }
    float g6[2];
#pragma unroll
    for (int o = 0; o < 2; ++o) {
        float a = 0.f;
#pragma unroll
        for (int c = 0; c < 4; ++c) a = fmaf(lds_tw[160 + o * 4 + c], g5[c], a);
        g6[o] = leaky(a);
    }
    out[px0 + lane] = fmaf(lds_tw[168], g6[0], lds_tw[169] * g6[1]);
}

extern "C" void kernel_launch(void* const* d_in, const int* in_sizes, int n_in,
                              void* d_out, int out_size, void* d_ws, size_t ws_size,
                              hipStream_t stream) {
    const float* x  = (const float*)d_in[0];
    const float* w1 = (const float*)d_in[1];
    const float* w2 = (const float*)d_in[2];
    const float* w3 = (const float*)d_in[3];
    const float* w4 = (const float*)d_in[4];
    const float* w5 = (const float*)d_in[5];
    const float* w6 = (const float*)d_in[6];
    const float* w7 = (const float*)d_in[7];
    float* out = (float*)d_out;

    const int P = 8 * 256 * 256;  // 524288 px; 1 wave (64 px) per block
    fused_wave_kernel<<<P / 64, 64, 0, stream>>>(x, w1, w2, w3, w4, w5, w6, w7, out);
}